// Round 17
// baseline (289.048 us; speedup 1.0000x reference)
//
#include <hip/hip_runtime.h>
#include <cstdint>

typedef unsigned short u16;
typedef uint32_t u32;
typedef float f32x4 __attribute__((ext_vector_type(4)));
typedef short s16x8 __attribute__((ext_vector_type(8)));
typedef u16 u16x4 __attribute__((ext_vector_type(4)));
typedef u32 u32x2 __attribute__((ext_vector_type(2)));
typedef u32 u32x4 __attribute__((ext_vector_type(4)));

__device__ __forceinline__ u16 f2bf(float f) {
  u32 u = __builtin_bit_cast(u32, f);
  u += 0x7FFFu + ((u >> 16) & 1u);
  return (u16)(u >> 16);
}

__device__ __forceinline__ u32 pack2bf_trunc(float lo, float hi) {
  return __builtin_amdgcn_perm(__builtin_bit_cast(u32, hi),
                               __builtin_bit_cast(u32, lo), 0x07060302u);
}

template <typename T>
__device__ __forceinline__ T ldv(const void* p) {
  T v;
  __builtin_memcpy(&v, __builtin_assume_aligned(p, 16), sizeof(T));
  return v;
}

__device__ __forceinline__ void gload_lds16(const void* g, void* l) {
  __builtin_amdgcn_global_load_lds((const __attribute__((address_space(1))) void*)g,
                                   (__attribute__((address_space(3))) void*)l, 16, 0, 0);
}

// ---------------- convert x (fp32 -> bf16) ----------------
__global__ __launch_bounds__(256) void cvt_x_k(const float* __restrict__ in,
                                               u16* __restrict__ out) {
  const int i = (blockIdx.x * 256 + threadIdx.x) * 4;
  float4 v = *(const float4*)(in + i);
  u16x4 o;
  o.x = f2bf(v.x); o.y = f2bf(v.y); o.z = f2bf(v.z); o.w = f2bf(v.w);
  *(u16x4*)(out + i) = o;
}

// ---------------- transpose weights (fp32 [K][N] -> bf16 [N][K]) ----------------
__global__ __launch_bounds__(256) void prep_w_k(const float* __restrict__ Wq,
                                                const float* __restrict__ Wk,
                                                const float* __restrict__ Wv,
                                                const float* __restrict__ Wo,
                                                u16* __restrict__ out) {
  __shared__ u16 t[64][72];
  const float* W = (blockIdx.z == 0) ? Wq : (blockIdx.z == 1) ? Wk
                  : (blockIdx.z == 2) ? Wv : Wo;
  u16* O = out + (size_t)blockIdx.z * 1024 * 1024;
  const int n0 = blockIdx.x * 64, k0 = blockIdx.y * 64;
  const int tid = threadIdx.x;
#pragma unroll
  for (int i = 0; i < 16; ++i) {
    int e = i * 256 + tid;
    int r = e >> 6, c = e & 63;
    t[r][c] = f2bf(W[(size_t)(k0 + r) * 1024 + n0 + c]);
  }
  __syncthreads();
#pragma unroll
  for (int i = 0; i < 16; ++i) {
    int e = i * 256 + tid;
    int rr = e >> 6, cc = e & 63;
    O[(size_t)(n0 + rr) * 1024 + k0 + cc] = t[cc][rr];
  }
}

// ---------------- fused QKV GEMM: 256x384 tile + coalesced LDS epilogue (r17) ----
// Staged reads 320MB (vs r13's 576); r16's scatter-write regression fixed by
// porting r13's LDS-staged 16B-store epilogue: 6 passes of 64 cols, pass p is
// written by (wn,ni) blocks with (wn*96+ni*16)>>6 == p (each 16-col block in
// exactly one pass), then all 512 threads store with the validated r13 code.
// grid (32,8) = 256 blocks = exactly 1 round. 8 waves 2M x 4N, acc[8][6].
__global__ __launch_bounds__(512, 1) void gemm_qkv_k(const u16* __restrict__ A,
                                                     const u16* __restrict__ Wt,
                                                     const float* __restrict__ bq,
                                                     const float* __restrict__ bk,
                                                     const float* __restrict__ bv,
                                                     u16* __restrict__ Qh,
                                                     u16* __restrict__ Kh,
                                                     u16* __restrict__ Vt,
                                                     float qscale) {
  constexpr int K = 1024;
  __shared__ __attribute__((aligned(16))) u16 As[2][256][64];   // 64 KB
  __shared__ __attribute__((aligned(16))) u16 Bs[2][384][64];   // 96 KB
  const int tid = threadIdx.x;
  const int l = tid & 63, w = tid >> 6;
  const int lr = l & 15, lg = l >> 4;
  const int wm = w >> 2, wn = w & 3;            // 2M x 4N
  const int m0 = blockIdx.x * 256;
  const int by = blockIdx.y;                    // n-panel of 384 (0..7)
  const int rT = tid >> 3;                      // 0..63 staging row
  const int cSw = (((tid & 7) ^ (rT & 7)) << 3);
  const int xk = lr & 7;

  f32x4 acc[8][6] = {};

#define GSTAGE(buf, kt)                                                         \
  do {                                                                          \
    _Pragma("unroll")                                                           \
    for (int i = 0; i < 4; ++i)                                                 \
      gload_lds16(A + (size_t)(m0 + i * 64 + rT) * K + (kt) + cSw,              \
                  &As[buf][i * 64][0] + (size_t)w * 512);                       \
    _Pragma("unroll")                                                           \
    for (int i = 0; i < 6; ++i)                                                 \
      gload_lds16(Wt + (size_t)(by * 384 + i * 64 + rT) * K + (kt) + cSw,       \
                  &Bs[buf][i * 64][0] + (size_t)w * 512);                       \
  } while (0)

  GSTAGE(0, 0);
  asm volatile("s_waitcnt vmcnt(0)" ::: "memory");
  __builtin_amdgcn_s_barrier();

  for (int t = 0; t < 16; ++t) {
    const int cur = t & 1;
    if (t < 15) {
      GSTAGE(cur ^ 1, (t + 1) * 64);
      asm volatile("s_waitcnt vmcnt(10)" ::: "memory");  // retires S(t)
    } else {
      asm volatile("s_waitcnt vmcnt(0)" ::: "memory");
    }
    __builtin_amdgcn_s_barrier();
#pragma unroll
    for (int kk = 0; kk < 2; ++kk) {
      s16x8 b[6];
#pragma unroll
      for (int ni = 0; ni < 6; ++ni)
        b[ni] = ldv<s16x8>(&Bs[cur][wn * 96 + ni * 16 + lr][((kk * 4 + lg) ^ xk) << 3]);
#pragma unroll
      for (int mi = 0; mi < 8; ++mi) {
        s16x8 a = ldv<s16x8>(&As[cur][wm * 128 + mi * 16 + lr][((kk * 4 + lg) ^ xk) << 3]);
#pragma unroll
        for (int ni = 0; ni < 6; ++ni)
          acc[mi][ni] = __builtin_amdgcn_mfma_f32_16x16x32_bf16(a, b[ni], acc[mi][ni], 0, 0, 0);
      }
    }
    __builtin_amdgcn_s_barrier();  // buf t reads done before its overwrite (issued t+1)
  }
#undef GSTAGE

  // ---- coalesced epilogue: 6 passes of 64 cols via swizzled staging in As[0] ----
  u16* Cb = &As[0][0][0];  // [256][64] u16 = 32 KB
  const int bb = m0 >> 11;
  const int sbase = m0 & 2047;

#pragma unroll
  for (int p = 0; p < 6; ++p) {
    __syncthreads();
#pragma unroll
    for (int ni = 0; ni < 6; ++ni) {
      const int gc = wn * 96 + ni * 16;  // 16-aligned, in exactly one 64-group
      if ((gc >> 6) == p) {
        const int cl = gc & 63;
        const int colg = by * 384 + gc;
        const int seg = colg >> 10;
        const float* bias = (seg == 0) ? bq : (seg == 1) ? bk : bv;
        const float scale = (seg == 0) ? qscale : 1.0f;
        const float bvv = bias[(colg & 1023) + lr];
#pragma unroll
        for (int mi = 0; mi < 8; ++mi)
#pragma unroll
          for (int r = 0; r < 4; ++r) {
            const int row = wm * 128 + mi * 16 + lg * 4 + r;
            const int c = cl + lr;
            Cb[row * 64 + ((((c >> 3) ^ (row & 7)) << 3) | (c & 7))] =
                f2bf((acc[mi][ni][r] + bvv) * scale);
          }
      }
    }
    __syncthreads();
    const int gp = by * 384 + p * 64;     // 64-aligned global col base
    const int seg = gp >> 10;
    u16* outp = (seg == 0) ? Qh : (seg == 1) ? Kh : Vt;
    const int h = (gp & 1023) >> 6;
    if (seg <= 1) {
      const int row = tid >> 1;           // 0..255
      const int s = sbase + row;
#pragma unroll
      for (int j = 0; j < 4; ++j) {
        const int c = (tid & 1) * 32 + j * 8;
        s16x8 v = ldv<s16x8>(&Cb[row * 64 + (((c >> 3) ^ (row & 7)) << 3)]);
        const int chunk = (seg == 0) ? (c >> 3) : (((c >> 3) ^ (s & 7)) & 7);
        *(s16x8*)(outp + ((size_t)((bb << 4) + h) * 2048 + s) * 64 + (chunk << 3)) = v;
      }
    } else {
      const int hd = tid & 63;
#pragma unroll
      for (int j = 0; j < 4; ++j) {
        const int s0 = (tid >> 6) * 32 + j * 8;  // 0..248
        u16 vals[8];
#pragma unroll
        for (int i = 0; i < 8; ++i) {
          const int row = s0 + i;
          vals[i] = Cb[row * 64 + ((((hd >> 3) ^ (row & 7)) << 3) | (hd & 7))];
        }
        const int sl = sbase + s0;
        const int swz = (((sl >> 3) & 7) ^ (hd & 7)) & 7;
        *(s16x8*)(outp + ((size_t)((bb << 4) + h) * 64 + hd) * 2048 +
                  ((sl & ~63) | (swz << 3))) = *(s16x8*)vals;
      }
    }
  }
}

// ---------------- final GEMM: 256x128, triple-buffered, de-pinned (r13) ----------
__global__ __launch_bounds__(512, 2) void gemm_o_k(const u16* __restrict__ A,
                                                   const u16* __restrict__ Bt,
                                                   const float* __restrict__ bias,
                                                   float* __restrict__ outp) {
  constexpr int K = 1024;
  __shared__ __attribute__((aligned(16))) u16 As[3][256][64];
  __shared__ __attribute__((aligned(16))) u16 Bs[3][128][64];
  const int tid = threadIdx.x;
  const int l = tid & 63, w = tid >> 6;
  const int lr = l & 15, lg = l >> 4;
  const int m0 = blockIdx.x * 256, n0 = blockIdx.y * 128;
  const int wr = (w >> 1) * 64, wc = (w & 1) * 64;
  const int rT = tid >> 3;
  const int cSw = (((tid & 7) ^ (rT & 7)) << 3);

  f32x4 acc[4][4] = {};

#define GSTAGE(buf, kt)                                                         \
  do {                                                                          \
    _Pragma("unroll")                                                           \
    for (int i = 0; i < 4; ++i)                                                 \
      gload_lds16(A + (size_t)(m0 + i * 64 + rT) * K + (kt) + cSw,              \
                  &As[buf][i * 64][0] + (size_t)w * 512);                       \
    _Pragma("unroll")                                                           \
    for (int i = 0; i < 2; ++i)                                                 \
      gload_lds16(Bt + (size_t)(n0 + i * 64 + rT) * K + (kt) + cSw,             \
                  &Bs[buf][i * 64][0] + (size_t)w * 512);                       \
  } while (0)

  GSTAGE(0, 0);
  GSTAGE(1, 64);
  asm volatile("s_waitcnt vmcnt(6)" ::: "memory");
  __builtin_amdgcn_s_barrier();

  int bcur = 0, bst = 2;
  for (int t = 0; t < 16; ++t) {
    if (t < 14) {
      GSTAGE(bst, (t + 2) * 64);
      asm volatile("s_waitcnt vmcnt(12)" ::: "memory");
    } else if (t == 14) {
      asm volatile("s_waitcnt vmcnt(6)" ::: "memory");
    } else {
      asm volatile("s_waitcnt vmcnt(0)" ::: "memory");
    }
    __builtin_amdgcn_s_barrier();
#pragma unroll
    for (int kk = 0; kk < 2; ++kk) {
      s16x8 a[4], b[4];
#pragma unroll
      for (int mi = 0; mi < 4; ++mi)
        a[mi] = ldv<s16x8>(&As[bcur][wr + mi * 16 + lr][((kk * 4 + lg) ^ (lr & 7)) << 3]);
#pragma unroll
      for (int ni = 0; ni < 4; ++ni)
        b[ni] = ldv<s16x8>(&Bs[bcur][wc + ni * 16 + lr][((kk * 4 + lg) ^ (lr & 7)) << 3]);
#pragma unroll
      for (int mi = 0; mi < 4; ++mi)
#pragma unroll
        for (int ni = 0; ni < 4; ++ni)
          acc[mi][ni] = __builtin_amdgcn_mfma_f32_16x16x32_bf16(a[mi], b[ni], acc[mi][ni], 0, 0, 0);
    }
    __builtin_amdgcn_s_barrier();
    bcur = (bcur == 2) ? 0 : bcur + 1;
    bst = (bst == 2) ? 0 : bst + 1;
  }
#undef GSTAGE

#pragma unroll
  for (int ni = 0; ni < 4; ++ni) {
    const int col = n0 + wc + ni * 16 + lr;
    const float bv = bias[col];
#pragma unroll
    for (int mi = 0; mi < 4; ++mi)
#pragma unroll
      for (int r = 0; r < 4; ++r) {
        const int rowm = m0 + wr + mi * 16 + lg * 4 + r;
        outp[(size_t)rowm * 1024 + col] = acc[mi][ni][r] + bv;
      }
  }
}

// ---------------- flash attention v8: 8 waves, 512 q-rows/block (r16, kept) --------
__global__ __launch_bounds__(512, 1) void attn_k(const u16* __restrict__ Qh,
                                                 const u16* __restrict__ Kg,
                                                 const u16* __restrict__ Vg,
                                                 u16* __restrict__ Oattn) {
  __shared__ __attribute__((aligned(16))) u16 Kbuf[2][4096];
  __shared__ __attribute__((aligned(16))) u16 Vbuf[2][4096];
  __shared__ __attribute__((aligned(16))) u16 P_lds[8][16][64];
  const int tid = threadIdx.x, l = tid & 63, w = tid >> 6;
  const int lr = l & 15, lg = l >> 4;
  const int bh = blockIdx.y;
  const int q0 = blockIdx.x * 512 + w * 64;
  const u16* Q = Qh + (size_t)bh * (2048 * 64);
  const u16* K = Kg + (size_t)bh * (2048 * 64);
  const u16* V = Vg + (size_t)bh * (64 * 2048);

  s16x8 qf[4][2];
#pragma unroll
  for (int f = 0; f < 4; ++f)
#pragma unroll
    for (int kk = 0; kk < 2; ++kk)
      qf[f][kk] = ldv<s16x8>(Q + (size_t)(q0 + f * 16 + lr) * 64 + kk * 32 + lg * 8);

  const u32 one2 = 0x3F803F80u;  // two bf16 1.0
  const s16x8 onesv = __builtin_bit_cast(s16x8, (u32x4){one2, one2, one2, one2});

  f32x4 acc[4][4] = {};
  f32x4 lsum[4] = {};

#define STAGE(buf, kv0)                                                                 \
  do {                                                                                  \
    gload_lds16(K + (size_t)(kv0) * 64 + (size_t)tid * 8, &Kbuf[buf][w * 512]);         \
    gload_lds16(V + (size_t)(tid >> 3) * 2048 + (kv0) + (tid & 7) * 8,                  \
                &Vbuf[buf][w * 512]);                                                   \
  } while (0)

  STAGE(0, 0);

  for (int t = 0; t < 32; ++t) {
    const int cur = t & 1;
    if (t < 31) {
      STAGE(cur ^ 1, (t + 1) * 64);
      asm volatile("s_waitcnt vmcnt(2)" ::: "memory");  // cur's 2 retired
    } else {
      asm volatile("s_waitcnt vmcnt(0)" ::: "memory");
    }
    __builtin_amdgcn_s_barrier();

    s16x8 pf[4][2];
#pragma unroll
    for (int kvc = 0; kvc < 2; ++kvc) {
      f32x4 s2[4][2] = {};
      __builtin_amdgcn_s_setprio(1);
#pragma unroll
      for (int t2 = 0; t2 < 2; ++t2) {
        const int tt = kvc * 2 + t2;
        s16x8 k0 = ldv<s16x8>(&Kbuf[cur][(tt * 16 + lr) * 64 + ((lg ^ (lr & 7)) << 3)]);
        s16x8 k1 = ldv<s16x8>(&Kbuf[cur][(tt * 16 + lr) * 64 + (((4 + lg) ^ (lr & 7)) << 3)]);
#pragma unroll
        for (int f = 0; f < 4; ++f) {
          s2[f][t2] = __builtin_amdgcn_mfma_f32_16x16x32_bf16(k0, qf[f][0], s2[f][t2], 0, 0, 0);
          s2[f][t2] = __builtin_amdgcn_mfma_f32_16x16x32_bf16(k1, qf[f][1], s2[f][t2], 0, 0, 0);
        }
      }
      __builtin_amdgcn_s_setprio(0);

#pragma unroll
      for (int f = 0; f < 4; ++f) {
#pragma unroll
        for (int t2 = 0; t2 < 2; ++t2)
#pragma unroll
          for (int r = 0; r < 4; ++r)
            s2[f][t2][r] = __builtin_amdgcn_exp2f(s2[f][t2][r]);
#pragma unroll
        for (int t2 = 0; t2 < 2; ++t2) {
          const int tt = kvc * 2 + t2;
          u32x2 pw;
          pw.x = pack2bf_trunc(s2[f][t2][0], s2[f][t2][1]);
          pw.y = pack2bf_trunc(s2[f][t2][2], s2[f][t2][3]);
          const int off = (((tt * 2 + (lg >> 1)) ^ (lr & 7)) << 3) + ((lg & 1) << 2);
          *(u32x2*)&P_lds[w][lr][off] = pw;
        }
        pf[f][kvc] = ldv<s16x8>(&P_lds[w][lr][((kvc * 4 + lg) ^ (lr & 7)) << 3]);
        lsum[f] = __builtin_amdgcn_mfma_f32_16x16x32_bf16(pf[f][kvc], onesv, lsum[f], 0, 0, 0);
      }
    }

    __builtin_amdgcn_s_setprio(1);
#pragma unroll
    for (int dt = 0; dt < 4; ++dt) {
      s16x8 v0 = ldv<s16x8>(&Vbuf[cur][(dt * 16 + lr) * 64 + ((lg ^ (lr & 7)) << 3)]);
      s16x8 v1 = ldv<s16x8>(&Vbuf[cur][(dt * 16 + lr) * 64 + (((4 + lg) ^ (lr & 7)) << 3)]);
#pragma unroll
      for (int f = 0; f < 4; ++f) {
        acc[f][dt] = __builtin_amdgcn_mfma_f32_16x16x32_bf16(pf[f][0], v0, acc[f][dt], 0, 0, 0);
        acc[f][dt] = __builtin_amdgcn_mfma_f32_16x16x32_bf16(pf[f][1], v1, acc[f][dt], 0, 0, 0);
      }
    }
    __builtin_amdgcn_s_setprio(0);
    __builtin_amdgcn_s_barrier();
  }
#undef STAGE

  const int b = bh >> 4, h = bh & 15;
#pragma unroll
  for (int f = 0; f < 4; ++f) {
    float li[4];
#pragma unroll
    for (int r = 0; r < 4; ++r) li[r] = __builtin_amdgcn_rcpf(lsum[f][r]);
#pragma unroll
    for (int dt = 0; dt < 4; ++dt)
#pragma unroll
      for (int r = 0; r < 4; ++r) {
        const int q = q0 + f * 16 + lg * 4 + r;
        Oattn[(size_t)((b << 11) + q) * 1024 + (h << 6) + dt * 16 + lr] =
            f2bf(acc[f][dt][r] * li[r]);
      }
  }
}

extern "C" void kernel_launch(void* const* d_in, const int* in_sizes, int n_in,
                              void* d_out, int out_size, void* d_ws, size_t ws_size,
                              hipStream_t stream) {
  const float* x  = (const float*)d_in[0];
  const float* Wq = (const float*)d_in[1];
  const float* bq = (const float*)d_in[2];
  const float* Wk = (const float*)d_in[3];
  const float* bk = (const float*)d_in[4];
  const float* Wv = (const float*)d_in[5];
  const float* bv = (const float*)d_in[6];
  const float* Wo = (const float*)d_in[7];
  const float* bo = (const float*)d_in[8];

  char* ws = (char*)d_ws;
  const size_t MB = 1u << 20;
  u16* xb = (u16*)(ws);              // 16 MB: x bf16 [8192][1024]
  u16* wt = (u16*)(ws + 16 * MB);    // 8 MB: 4x transposed bf16 weights [N][K]
  u16* Qh = (u16*)(ws + 24 * MB);    // 16 MB
  u16* Kh = (u16*)(ws + 40 * MB);    // 16 MB (swizzled)
  u16* Vt = (u16*)(ws + 56 * MB);    // 16 MB (transposed, swizzled)
  u16* attn = xb;                    // alias: x no longer needed after QKV GEMM

  const float qscale = 0.125f * 1.44269504088896f;  // fold 1/sqrt(64) and log2(e)

  cvt_x_k<<<dim3(8192), dim3(256), 0, stream>>>(x, xb);
  prep_w_k<<<dim3(16, 16, 4), dim3(256), 0, stream>>>(Wq, Wk, Wv, Wo, wt);
  gemm_qkv_k<<<dim3(32, 8), dim3(512), 0, stream>>>(xb, wt, bq, bk, bv, Qh, Kh, Vt, qscale);
  attn_k<<<dim3(4, 64), dim3(512), 0, stream>>>(Qh, Kh, Vt, attn);
  gemm_o_k<<<dim3(32, 8), dim3(512), 0, stream>>>(attn, wt + 3 * 1048576, bo, (float*)d_out);
}

// Round 18
// 201.966 us; speedup vs baseline: 1.4312x; 1.4312x over previous
//
#include <hip/hip_runtime.h>
#include <cstdint>

typedef unsigned short u16;
typedef uint32_t u32;
typedef float f32x4 __attribute__((ext_vector_type(4)));
typedef short s16x8 __attribute__((ext_vector_type(8)));
typedef u16 u16x4 __attribute__((ext_vector_type(4)));
typedef u32 u32x2 __attribute__((ext_vector_type(2)));
typedef u32 u32x4 __attribute__((ext_vector_type(4)));

__device__ __forceinline__ u16 f2bf(float f) {
  u32 u = __builtin_bit_cast(u32, f);
  u += 0x7FFFu + ((u >> 16) & 1u);
  return (u16)(u >> 16);
}

__device__ __forceinline__ u32 pack2bf_trunc(float lo, float hi) {
  return __builtin_amdgcn_perm(__builtin_bit_cast(u32, hi),
                               __builtin_bit_cast(u32, lo), 0x07060302u);
}

template <typename T>
__device__ __forceinline__ T ldv(const void* p) {
  T v;
  __builtin_memcpy(&v, __builtin_assume_aligned(p, 16), sizeof(T));
  return v;
}

__device__ __forceinline__ void gload_lds16(const void* g, void* l) {
  __builtin_amdgcn_global_load_lds((const __attribute__((address_space(1))) void*)g,
                                   (__attribute__((address_space(3))) void*)l, 16, 0, 0);
}

// ---------------- convert x (fp32 -> bf16) ----------------
__global__ __launch_bounds__(256) void cvt_x_k(const float* __restrict__ in,
                                               u16* __restrict__ out) {
  const int i = (blockIdx.x * 256 + threadIdx.x) * 4;
  float4 v = *(const float4*)(in + i);
  u16x4 o;
  o.x = f2bf(v.x); o.y = f2bf(v.y); o.z = f2bf(v.z); o.w = f2bf(v.w);
  *(u16x4*)(out + i) = o;
}

// ---------------- transpose weights (fp32 [K][N] -> bf16 [N][K]) ----------------
__global__ __launch_bounds__(256) void prep_w_k(const float* __restrict__ Wq,
                                                const float* __restrict__ Wk,
                                                const float* __restrict__ Wv,
                                                const float* __restrict__ Wo,
                                                u16* __restrict__ out) {
  __shared__ u16 t[64][72];
  const float* W = (blockIdx.z == 0) ? Wq : (blockIdx.z == 1) ? Wk
                  : (blockIdx.z == 2) ? Wv : Wo;
  u16* O = out + (size_t)blockIdx.z * 1024 * 1024;
  const int n0 = blockIdx.x * 64, k0 = blockIdx.y * 64;
  const int tid = threadIdx.x;
#pragma unroll
  for (int i = 0; i < 16; ++i) {
    int e = i * 256 + tid;
    int r = e >> 6, c = e & 63;
    t[r][c] = f2bf(W[(size_t)(k0 + r) * 1024 + n0 + c]);
  }
  __syncthreads();
#pragma unroll
  for (int i = 0; i < 16; ++i) {
    int e = i * 256 + tid;
    int rr = e >> 6, cc = e & 63;
    O[(size_t)(n0 + rr) * 1024 + k0 + cc] = t[cc][rr];
  }
}

// ---------------- fused QKV GEMM: 256x128, 8 waves, triple-buffered (r13 best) ----
// At its staged-byte floor: 576MB / ~6.4 TB/s L3 ~= 90us (measured 91.4).
// De-pinned: vmcnt asm ("memory") + raw s_barrier only. T2 swizzle both-sides.
__global__ __launch_bounds__(512, 2) void gemm_qkv_k(const u16* __restrict__ A,
                                                     const u16* __restrict__ Wt,
                                                     const float* __restrict__ bq,
                                                     const float* __restrict__ bk,
                                                     const float* __restrict__ bv,
                                                     u16* __restrict__ Qh,
                                                     u16* __restrict__ Kh,
                                                     u16* __restrict__ Vt,
                                                     float qscale) {
  constexpr int K = 1024;
  __shared__ __attribute__((aligned(16))) u16 As[3][256][64];
  __shared__ __attribute__((aligned(16))) u16 Bs[3][128][64];
  const int tid = threadIdx.x;
  const int l = tid & 63, w = tid >> 6;
  const int lr = l & 15, lg = l >> 4;
  const int m0 = blockIdx.x * 256;
  const int ng = blockIdx.y * 128;
  const int seg = ng >> 10;
  const int n0 = ng & 1023;
  const u16* Bt = Wt + ((size_t)seg << 20);
  const int wr = (w >> 1) * 64, wc = (w & 1) * 64;
  const int rT = tid >> 3;
  const int cSw = (((tid & 7) ^ (rT & 7)) << 3);

  f32x4 acc[4][4] = {};

#define GSTAGE(buf, kt)                                                         \
  do {                                                                          \
    _Pragma("unroll")                                                           \
    for (int i = 0; i < 4; ++i)                                                 \
      gload_lds16(A + (size_t)(m0 + i * 64 + rT) * K + (kt) + cSw,              \
                  &As[buf][i * 64][0] + (size_t)w * 512);                       \
    _Pragma("unroll")                                                           \
    for (int i = 0; i < 2; ++i)                                                 \
      gload_lds16(Bt + (size_t)(n0 + i * 64 + rT) * K + (kt) + cSw,             \
                  &Bs[buf][i * 64][0] + (size_t)w * 512);                       \
  } while (0)

  GSTAGE(0, 0);
  GSTAGE(1, 64);
  asm volatile("s_waitcnt vmcnt(6)" ::: "memory");
  __builtin_amdgcn_s_barrier();

  int bcur = 0, bst = 2;
  for (int t = 0; t < 16; ++t) {
    if (t < 14) {
      GSTAGE(bst, (t + 2) * 64);
      asm volatile("s_waitcnt vmcnt(12)" ::: "memory");
    } else if (t == 14) {
      asm volatile("s_waitcnt vmcnt(6)" ::: "memory");
    } else {
      asm volatile("s_waitcnt vmcnt(0)" ::: "memory");
    }
    __builtin_amdgcn_s_barrier();
#pragma unroll
    for (int kk = 0; kk < 2; ++kk) {
      s16x8 a[4], b[4];
#pragma unroll
      for (int mi = 0; mi < 4; ++mi)
        a[mi] = ldv<s16x8>(&As[bcur][wr + mi * 16 + lr][((kk * 4 + lg) ^ (lr & 7)) << 3]);
#pragma unroll
      for (int ni = 0; ni < 4; ++ni)
        b[ni] = ldv<s16x8>(&Bs[bcur][wc + ni * 16 + lr][((kk * 4 + lg) ^ (lr & 7)) << 3]);
#pragma unroll
      for (int mi = 0; mi < 4; ++mi)
#pragma unroll
        for (int ni = 0; ni < 4; ++ni)
          acc[mi][ni] = __builtin_amdgcn_mfma_f32_16x16x32_bf16(a[mi], b[ni], acc[mi][ni], 0, 0, 0);
    }
    __builtin_amdgcn_s_barrier();  // buf t reads retired before its overwrite (issued t+1)
    bcur = (bcur == 2) ? 0 : bcur + 1;
    bst = (bst == 2) ? 0 : bst + 1;
  }
#undef GSTAGE

  const float* bias = (seg == 0) ? bq : (seg == 1) ? bk : bv;
  const float scale = (seg == 0) ? qscale : 1.0f;
  u16* outp = (seg == 0) ? Qh : (seg == 1) ? Kh : Vt;

  // ---- coalesced epilogue via swizzled LDS staging (reuse As[0]: [256][64]) ----
  u16* Cb = &As[0][0][0];
  const int bb = m0 >> 11;
  const int sbase = m0 & 2047;

#pragma unroll
  for (int p = 0; p < 2; ++p) {
    __syncthreads();
    if ((wc >> 6) == p) {
#pragma unroll
      for (int ni = 0; ni < 4; ++ni) {
        const int c = ni * 16 + lr;
        const float bvv = bias[n0 + p * 64 + c];
#pragma unroll
        for (int mi = 0; mi < 4; ++mi) {
#pragma unroll
          for (int r = 0; r < 4; ++r) {
            const int row = wr + mi * 16 + lg * 4 + r;
            Cb[row * 64 + ((((c >> 3) ^ (row & 7)) << 3) | (c & 7))] =
                f2bf((acc[mi][ni][r] + bvv) * scale);
          }
        }
      }
    }
    __syncthreads();
    const int h = (n0 + p * 64) >> 6;
    if (seg <= 1) {
      const int row = tid >> 1;
      const int s = sbase + row;
#pragma unroll
      for (int j2 = 0; j2 < 4; ++j2) {
        const int c = (tid & 1) * 32 + j2 * 8;
        s16x8 v = ldv<s16x8>(&Cb[row * 64 + (((c >> 3) ^ (row & 7)) << 3)]);
        const int chunk = (seg == 0) ? (c >> 3) : (((c >> 3) ^ (s & 7)) & 7);
        *(s16x8*)(outp + ((size_t)((bb << 4) + h) * 2048 + s) * 64 + (chunk << 3)) = v;
      }
    } else {
      const int hd = tid & 63;
#pragma unroll
      for (int j2 = 0; j2 < 4; ++j2) {
        const int s0 = (tid >> 6) * 32 + j2 * 8;
        u16 vals[8];
#pragma unroll
        for (int i = 0; i < 8; ++i) {
          const int row = s0 + i;
          vals[i] = Cb[row * 64 + ((((hd >> 3) ^ (row & 7)) << 3) | (hd & 7))];
        }
        const int sl = sbase + s0;
        const int swz = (((sl >> 3) & 7) ^ (hd & 7)) & 7;
        *(s16x8*)(outp + ((size_t)((bb << 4) + h) * 64 + hd) * 2048 +
                  ((sl & ~63) | (swz << 3))) = *(s16x8*)vals;
      }
    }
  }
}

// ---------------- final GEMM: 256x128, triple-buffered, de-pinned (r13) ----------
__global__ __launch_bounds__(512, 2) void gemm_o_k(const u16* __restrict__ A,
                                                   const u16* __restrict__ Bt,
                                                   const float* __restrict__ bias,
                                                   float* __restrict__ outp) {
  constexpr int K = 1024;
  __shared__ __attribute__((aligned(16))) u16 As[3][256][64];
  __shared__ __attribute__((aligned(16))) u16 Bs[3][128][64];
  const int tid = threadIdx.x;
  const int l = tid & 63, w = tid >> 6;
  const int lr = l & 15, lg = l >> 4;
  const int m0 = blockIdx.x * 256, n0 = blockIdx.y * 128;
  const int wr = (w >> 1) * 64, wc = (w & 1) * 64;
  const int rT = tid >> 3;
  const int cSw = (((tid & 7) ^ (rT & 7)) << 3);

  f32x4 acc[4][4] = {};

#define GSTAGE(buf, kt)                                                         \
  do {                                                                          \
    _Pragma("unroll")                                                           \
    for (int i = 0; i < 4; ++i)                                                 \
      gload_lds16(A + (size_t)(m0 + i * 64 + rT) * K + (kt) + cSw,              \
                  &As[buf][i * 64][0] + (size_t)w * 512);                       \
    _Pragma("unroll")                                                           \
    for (int i = 0; i < 2; ++i)                                                 \
      gload_lds16(Bt + (size_t)(n0 + i * 64 + rT) * K + (kt) + cSw,             \
                  &Bs[buf][i * 64][0] + (size_t)w * 512);                       \
  } while (0)

  GSTAGE(0, 0);
  GSTAGE(1, 64);
  asm volatile("s_waitcnt vmcnt(6)" ::: "memory");
  __builtin_amdgcn_s_barrier();

  int bcur = 0, bst = 2;
  for (int t = 0; t < 16; ++t) {
    if (t < 14) {
      GSTAGE(bst, (t + 2) * 64);
      asm volatile("s_waitcnt vmcnt(12)" ::: "memory");
    } else if (t == 14) {
      asm volatile("s_waitcnt vmcnt(6)" ::: "memory");
    } else {
      asm volatile("s_waitcnt vmcnt(0)" ::: "memory");
    }
    __builtin_amdgcn_s_barrier();
#pragma unroll
    for (int kk = 0; kk < 2; ++kk) {
      s16x8 a[4], b[4];
#pragma unroll
      for (int mi = 0; mi < 4; ++mi)
        a[mi] = ldv<s16x8>(&As[bcur][wr + mi * 16 + lr][((kk * 4 + lg) ^ (lr & 7)) << 3]);
#pragma unroll
      for (int ni = 0; ni < 4; ++ni)
        b[ni] = ldv<s16x8>(&Bs[bcur][wc + ni * 16 + lr][((kk * 4 + lg) ^ (lr & 7)) << 3]);
#pragma unroll
      for (int mi = 0; mi < 4; ++mi)
#pragma unroll
        for (int ni = 0; ni < 4; ++ni)
          acc[mi][ni] = __builtin_amdgcn_mfma_f32_16x16x32_bf16(a[mi], b[ni], acc[mi][ni], 0, 0, 0);
    }
    __builtin_amdgcn_s_barrier();
    bcur = (bcur == 2) ? 0 : bcur + 1;
    bst = (bst == 2) ? 0 : bst + 1;
  }
#undef GSTAGE

#pragma unroll
  for (int ni = 0; ni < 4; ++ni) {
    const int col = n0 + wc + ni * 16 + lr;
    const float bv = bias[col];
#pragma unroll
    for (int mi = 0; mi < 4; ++mi)
#pragma unroll
      for (int r = 0; r < 4; ++r) {
        const int rowm = m0 + wr + mi * 16 + lg * 4 + r;
        outp[(size_t)rowm * 1024 + col] = acc[mi][ni][r] + bv;
      }
  }
}

// ---------------- flash attention v8: 8 waves, 512 q-rows/block (r16 best) --------
__global__ __launch_bounds__(512, 1) void attn_k(const u16* __restrict__ Qh,
                                                 const u16* __restrict__ Kg,
                                                 const u16* __restrict__ Vg,
                                                 u16* __restrict__ Oattn) {
  __shared__ __attribute__((aligned(16))) u16 Kbuf[2][4096];
  __shared__ __attribute__((aligned(16))) u16 Vbuf[2][4096];
  __shared__ __attribute__((aligned(16))) u16 P_lds[8][16][64];
  const int tid = threadIdx.x, l = tid & 63, w = tid >> 6;
  const int lr = l & 15, lg = l >> 4;
  const int bh = blockIdx.y;
  const int q0 = blockIdx.x * 512 + w * 64;
  const u16* Q = Qh + (size_t)bh * (2048 * 64);
  const u16* K = Kg + (size_t)bh * (2048 * 64);
  const u16* V = Vg + (size_t)bh * (64 * 2048);

  s16x8 qf[4][2];
#pragma unroll
  for (int f = 0; f < 4; ++f)
#pragma unroll
    for (int kk = 0; kk < 2; ++kk)
      qf[f][kk] = ldv<s16x8>(Q + (size_t)(q0 + f * 16 + lr) * 64 + kk * 32 + lg * 8);

  const u32 one2 = 0x3F803F80u;  // two bf16 1.0
  const s16x8 onesv = __builtin_bit_cast(s16x8, (u32x4){one2, one2, one2, one2});

  f32x4 acc[4][4] = {};
  f32x4 lsum[4] = {};

#define STAGE(buf, kv0)                                                                 \
  do {                                                                                  \
    gload_lds16(K + (size_t)(kv0) * 64 + (size_t)tid * 8, &Kbuf[buf][w * 512]);         \
    gload_lds16(V + (size_t)(tid >> 3) * 2048 + (kv0) + (tid & 7) * 8,                  \
                &Vbuf[buf][w * 512]);                                                   \
  } while (0)

  STAGE(0, 0);

  for (int t = 0; t < 32; ++t) {
    const int cur = t & 1;
    if (t < 31) {
      STAGE(cur ^ 1, (t + 1) * 64);
      asm volatile("s_waitcnt vmcnt(2)" ::: "memory");  // cur's 2 retired
    } else {
      asm volatile("s_waitcnt vmcnt(0)" ::: "memory");
    }
    __builtin_amdgcn_s_barrier();

    s16x8 pf[4][2];
#pragma unroll
    for (int kvc = 0; kvc < 2; ++kvc) {
      f32x4 s2[4][2] = {};
      __builtin_amdgcn_s_setprio(1);
#pragma unroll
      for (int t2 = 0; t2 < 2; ++t2) {
        const int tt = kvc * 2 + t2;
        s16x8 k0 = ldv<s16x8>(&Kbuf[cur][(tt * 16 + lr) * 64 + ((lg ^ (lr & 7)) << 3)]);
        s16x8 k1 = ldv<s16x8>(&Kbuf[cur][(tt * 16 + lr) * 64 + (((4 + lg) ^ (lr & 7)) << 3)]);
#pragma unroll
        for (int f = 0; f < 4; ++f) {
          s2[f][t2] = __builtin_amdgcn_mfma_f32_16x16x32_bf16(k0, qf[f][0], s2[f][t2], 0, 0, 0);
          s2[f][t2] = __builtin_amdgcn_mfma_f32_16x16x32_bf16(k1, qf[f][1], s2[f][t2], 0, 0, 0);
        }
      }
      __builtin_amdgcn_s_setprio(0);

#pragma unroll
      for (int f = 0; f < 4; ++f) {
#pragma unroll
        for (int t2 = 0; t2 < 2; ++t2)
#pragma unroll
          for (int r = 0; r < 4; ++r)
            s2[f][t2][r] = __builtin_amdgcn_exp2f(s2[f][t2][r]);
#pragma unroll
        for (int t2 = 0; t2 < 2; ++t2) {
          const int tt = kvc * 2 + t2;
          u32x2 pw;
          pw.x = pack2bf_trunc(s2[f][t2][0], s2[f][t2][1]);
          pw.y = pack2bf_trunc(s2[f][t2][2], s2[f][t2][3]);
          const int off = (((tt * 2 + (lg >> 1)) ^ (lr & 7)) << 3) + ((lg & 1) << 2);
          *(u32x2*)&P_lds[w][lr][off] = pw;
        }
        pf[f][kvc] = ldv<s16x8>(&P_lds[w][lr][((kvc * 4 + lg) ^ (lr & 7)) << 3]);
        lsum[f] = __builtin_amdgcn_mfma_f32_16x16x32_bf16(pf[f][kvc], onesv, lsum[f], 0, 0, 0);
      }
    }

    __builtin_amdgcn_s_setprio(1);
#pragma unroll
    for (int dt = 0; dt < 4; ++dt) {
      s16x8 v0 = ldv<s16x8>(&Vbuf[cur][(dt * 16 + lr) * 64 + ((lg ^ (lr & 7)) << 3)]);
      s16x8 v1 = ldv<s16x8>(&Vbuf[cur][(dt * 16 + lr) * 64 + (((4 + lg) ^ (lr & 7)) << 3)]);
#pragma unroll
      for (int f = 0; f < 4; ++f) {
        acc[f][dt] = __builtin_amdgcn_mfma_f32_16x16x32_bf16(pf[f][0], v0, acc[f][dt], 0, 0, 0);
        acc[f][dt] = __builtin_amdgcn_mfma_f32_16x16x32_bf16(pf[f][1], v1, acc[f][dt], 0, 0, 0);
      }
    }
    __builtin_amdgcn_s_setprio(0);
    __builtin_amdgcn_s_barrier();
  }
#undef STAGE

  const int b = bh >> 4, h = bh & 15;
#pragma unroll
  for (int f = 0; f < 4; ++f) {
    float li[4];
#pragma unroll
    for (int r = 0; r < 4; ++r) li[r] = __builtin_amdgcn_rcpf(lsum[f][r]);
#pragma unroll
    for (int dt = 0; dt < 4; ++dt)
#pragma unroll
      for (int r = 0; r < 4; ++r) {
        const int q = q0 + f * 16 + lg * 4 + r;
        Oattn[(size_t)((b << 11) + q) * 1024 + (h << 6) + dt * 16 + lr] =
            f2bf(acc[f][dt][r] * li[r]);
      }
  }
}

extern "C" void kernel_launch(void* const* d_in, const int* in_sizes, int n_in,
                              void* d_out, int out_size, void* d_ws, size_t ws_size,
                              hipStream_t stream) {
  const float* x  = (const float*)d_in[0];
  const float* Wq = (const float*)d_in[1];
  const float* bq = (const float*)d_in[2];
  const float* Wk = (const float*)d_in[3];
  const float* bk = (const float*)d_in[4];
  const float* Wv = (const float*)d_in[5];
  const float* bv = (const float*)d_in[6];
  const float* Wo = (const float*)d_in[7];
  const float* bo = (const float*)d_in[8];

  char* ws = (char*)d_ws;
  const size_t MB = 1u << 20;
  u16* xb = (u16*)(ws);              // 16 MB: x bf16 [8192][1024]
  u16* wt = (u16*)(ws + 16 * MB);    // 8 MB: 4x transposed bf16 weights [N][K]
  u16* Qh = (u16*)(ws + 24 * MB);    // 16 MB
  u16* Kh = (u16*)(ws + 40 * MB);    // 16 MB (swizzled)
  u16* Vt = (u16*)(ws + 56 * MB);    // 16 MB (transposed, swizzled)
  u16* attn = xb;                    // alias: x no longer needed after QKV GEMM

  const float qscale = 0.125f * 1.44269504088896f;  // fold 1/sqrt(64) and log2(e)

  cvt_x_k<<<dim3(8192), dim3(256), 0, stream>>>(x, xb);
  prep_w_k<<<dim3(16, 16, 4), dim3(256), 0, stream>>>(Wq, Wk, Wv, Wo, wt);
  gemm_qkv_k<<<dim3(32, 24), dim3(512), 0, stream>>>(xb, wt, bq, bk, bv, Qh, Kh, Vt, qscale);
  attn_k<<<dim3(4, 64), dim3(512), 0, stream>>>(Qh, Kh, Vt, attn);
  gemm_o_k<<<dim3(32, 8), dim3(512), 0, stream>>>(attn, wt + 3 * 1048576, bo, (float*)d_out);
}